// Round 17
// baseline (165058.313 us; speedup 1.0000x reference)
//
#include <hip/hip_runtime.h>
#include <hip/hip_bf16.h>

typedef __hip_bfloat16 bf16;
typedef __attribute__((ext_vector_type(8))) short short8v;
typedef __attribute__((ext_vector_type(4))) float float4v;
#define DEVINL __device__ __forceinline__

DEVINL float bfu2f(unsigned int u){ union{unsigned int u; float f;} c; c.u=u; return c.f; }
DEVINL float b2f(bf16 v){ return __bfloat162float(v); }
DEVINL bf16  f2b(float f){ return __float2bfloat16(f); }
DEVINL float sigf(float x){ return 1.f/(1.f+__expf(-x)); }
DEVINL float tanhfast(float x){
  float t=__expf(-2.f*fabsf(x));
  float r=(1.f-t)/(1.f+t);
  return copysignf(r,x);
}
DEVINL void hilo(float x, short& h, short& l){
  bf16 hb = __float2bfloat16(x);
  bf16 lb = __float2bfloat16(x - __bfloat162float(hb));
  h = *(short*)&hb; l = *(short*)&lb;
}
DEVINL void ld4(const bf16* __restrict__ p, float* d){
  uint2 v = *reinterpret_cast<const uint2*>(p);
  d[0]=bfu2f(v.x<<16); d[1]=bfu2f(v.x&0xffff0000u);
  d[2]=bfu2f(v.y<<16); d[3]=bfu2f(v.y&0xffff0000u);
}
DEVINL void ld4(const float* __restrict__ p, float* d){
  float4 v = *reinterpret_cast<const float4*>(p);
  d[0]=v.x; d[1]=v.y; d[2]=v.z; d[3]=v.w;
}
DEVINL void st1(bf16* p, float v){ *p = f2b(v); }
DEVINL void st1(float* p, float v){ *p = v; }

// ---------- zero / prep ----------
__global__ void k_zero_f(float* p, long n){
  long i=(long)blockIdx.x*256+threadIdx.x, st=(long)gridDim.x*256;
  for(;i<n;i+=st) p[i]=0.f;
}
__global__ void k_zero_b(bf16* p, long n){
  long i=(long)blockIdx.x*256+threadIdx.x, st=(long)gridDim.x*256;
  for(;i<n;i+=st) p[i]=f2b(0.f);
}
// xTb[b*1600+t][d<96] = mel[b][d][t] (d>=80 -> 0), bf16
__global__ void k_xT96b(const float* __restrict__ mel, bf16* __restrict__ xT){
  int i = blockIdx.x*256+threadIdx.x; if(i>=51200*96) return;
  int m = i/96, d = i - m*96; int b = m/1600, t = m - b*1600;
  xT[i] = f2b((d<80)? mel[((size_t)b*80 + d)*1600 + t] : 0.f);
}
// [1024,80] f32 -> [1024,96] (hi,lo) bf16 zero-padded
__global__ void k_padW96b2(const float* __restrict__ W, bf16* __restrict__ hi,
                           bf16* __restrict__ lo){
  int i = blockIdx.x*256+threadIdx.x; if(i>=1024*96) return;
  int j=i/96, d=i-j*96;
  float x = (d<80)? W[j*80+d] : 0.f;
  short h,l; hilo(x,h,l);
  hi[i]=*(bf16*)&h; lo[i]=*(bf16*)&l;
}
// f32 -> bf16 cast (contiguous, single plane)
__global__ void k_cvt(const float* __restrict__ W, bf16* __restrict__ o, int n){
  int i=blockIdx.x*256+threadIdx.x; if(i<n) o[i]=f2b(W[i]);
}
// f32 -> (hi,lo) bf16 split (contiguous)
__global__ void k_cvt2(const float* __restrict__ W, bf16* __restrict__ hi,
                       bf16* __restrict__ lo, int n){
  int i=blockIdx.x*256+threadIdx.x; if(i>=n) return;
  short h,l; hilo(W[i], h, l);
  hi[i]=*(bf16*)&h; lo[i]=*(bf16*)&l;
}
// ps_W [101,512] -> [128,512] f32 zero-padded rows; ps_b -> [128]
__global__ void k_psW(const float* __restrict__ W, const float* __restrict__ bsrc,
                      float* __restrict__ Wp, float* __restrict__ bp){
  int i=blockIdx.x*256+threadIdx.x;
  if(i<128*512){ int n=i/512,k=i-n*512; Wp[i] = (n<101)? W[n*512+k] : 0.f; }
  else if(i<128*512+128){ int n=i-128*512; bp[n]=(n<101)? bsrc[n]:0.f; }
}
// dseqB[r=s*32+b][e] bf16 (rows < 5152; pad rows pre-zeroed)
__global__ void k_dseqb(const float* __restrict__ start, const float* __restrict__ dec_in,
                        bf16* __restrict__ dseq){
  int i=blockIdx.x*256+threadIdx.x; if(i>=5152*512) return;
  int r=i/512, e=i-r*512; int s=r/32, b=r-s*32;
  dseq[i] = f2b((s==0)? start[b*512+e] : dec_in[(size_t)b*81920 + e*160 + (s-1)]);
}
// w_pd = decWih[:, 0:512] hi/lo  ([2048,512])
__global__ void k_wpd(const float* __restrict__ Wih, bf16* __restrict__ hi,
                      bf16* __restrict__ lo){
  int i=blockIdx.x*256+threadIdx.x; if(i>=2048*512) return;
  int j=i>>9, k=i&511;
  short h,l; hilo(Wih[(size_t)j*1024 + k], h, l);
  hi[i]=*(bf16*)&h; lo[i]=*(bf16*)&l;
}

// ---------- scalar GEMM 64x64 (r8-verbatim; ph/ps only) ----------
template<bool RELU, typename TA, typename TCO>
__global__ __launch_bounds__(256) void gemm64(
    const TA* __restrict__ A, int lda, int T, int TC, int t0,
    const int* __restrict__ lens, int lenDiv, int rev,
    const float* __restrict__ W, int ldw,
    const float* __restrict__ bias,
    TCO* __restrict__ C, int ldc, int K)
{
  __shared__ float As[16][64];
  __shared__ float Ws[16][64];
  const int tid = threadIdx.x;
  const int n0 = blockIdx.x*64, m0 = blockIdx.y*64;
  const int tx = tid & 15, ty = tid >> 4;
  const int r = tid >> 2, c4 = (tid & 3) * 4;
  const int m = m0 + r;
  size_t arow;
  if (lens){
    int b = m / TC, tc = m - b*TC, t = t0 + tc;
    if (rev){
      int L = lens[b]; if (lenDiv==2) L=(L+1)>>1;
      t = L-1-t; if (t<0) t=0;
    }
    arow = (size_t)b*T + t;
  } else arow = (size_t)m;
  float acc[4][4] = {{0.f}};
  for (int k0=0; k0<K; k0+=16){
    float av[4];
    ld4(A + arow*lda + k0 + c4, av);
    const float4 wv = *reinterpret_cast<const float4*>(&W[(size_t)(n0+r)*ldw + k0 + c4]);
    As[c4+0][r] = av[0]; As[c4+1][r] = av[1]; As[c4+2][r] = av[2]; As[c4+3][r] = av[3];
    Ws[c4+0][r] = wv.x; Ws[c4+1][r]=wv.y; Ws[c4+2][r]=wv.z; Ws[c4+3][r]=wv.w;
    __syncthreads();
    #pragma unroll
    for(int k=0;k<16;k++){
      const float4 a = *reinterpret_cast<const float4*>(&As[k][ty*4]);
      const float4 w = *reinterpret_cast<const float4*>(&Ws[k][tx*4]);
      acc[0][0] += a.x*w.x; acc[0][1] += a.x*w.y; acc[0][2] += a.x*w.z; acc[0][3] += a.x*w.w;
      acc[1][0] += a.y*w.x; acc[1][1] += a.y*w.y; acc[1][2] += a.y*w.z; acc[1][3] += a.y*w.w;
      acc[2][0] += a.z*w.x; acc[2][1] += a.z*w.y; acc[2][2] += a.z*w.z; acc[2][3] += a.z*w.w;
      acc[3][0] += a.w*w.x; acc[3][1] += a.w*w.y; acc[3][2] += a.w*w.z; acc[3][3] += a.w*w.w;
    }
    __syncthreads();
  }
  #pragma unroll
  for(int i=0;i<4;i++){
    const size_t row = (size_t)m0 + ty*4 + i;
    #pragma unroll
    for(int j=0;j<4;j++){
      const int col = n0 + tx*4 + j;
      float v = acc[i][j] + (bias ? bias[col] : 0.f);
      if (RELU) v = fmaxf(v, 0.f);
      st1(&C[row*ldc + col], v);
    }
  }
}

// ---------- MFMA GEMM (bf16 A, hi/lo weights, 2 passes) — r12/r13-verified verbatim ----------
template<bool RELU, typename TCO>
__global__ __launch_bounds__(256) void gemmM(
    const bf16* __restrict__ A, int lda, int T, int TC, int t0,
    const int* __restrict__ lens, int lenDiv, int rev,
    const short* __restrict__ Whi, const short* __restrict__ Wlo, int ldw,
    const float* __restrict__ bias,
    TCO* __restrict__ C, int ldc, int K)
{
  __shared__ short As[128][40];
  __shared__ short Bs[2][128][40];
  const int tid = threadIdx.x;
  const int lane = tid & 63, wave = tid >> 6;
  const int wm = wave >> 1, wn = wave & 1;
  const int n0 = blockIdx.x*128, m0 = blockIdx.y*128;

  auto arow_of = [&](int m)->size_t{
    if (lens){
      int b = m / TC, tc = m - b*TC, t = t0 + tc;
      if (rev){ int L=lens[b]; if(lenDiv==2) L=(L+1)>>1; t=L-1-t; if(t<0)t=0; }
      return (size_t)b*T + t;
    }
    return (size_t)m;
  };

  float4v acc[4][4];
  #pragma unroll
  for (int i=0;i<4;++i)
    #pragma unroll
    for (int j=0;j<4;++j) acc[i][j] = (float4v){0.f,0.f,0.f,0.f};

  const int ar = tid>>2, akp = (tid&3)*8;
  const size_t arow0 = arow_of(m0 + ar), arow1 = arow_of(m0 + ar + 64);
  const short* Ash = (const short*)A;

  for (int k0=0; k0<K; k0+=32){
    *(short8v*)&As[ar][akp]    = *(const short8v*)(Ash + arow0*lda + k0 + akp);
    *(short8v*)&As[ar+64][akp] = *(const short8v*)(Ash + arow1*lda + k0 + akp);
    *(short8v*)&Bs[0][ar][akp]    = *(const short8v*)(Whi + (size_t)(n0+ar)*ldw + k0 + akp);
    *(short8v*)&Bs[0][ar+64][akp] = *(const short8v*)(Whi + (size_t)(n0+ar+64)*ldw + k0 + akp);
    *(short8v*)&Bs[1][ar][akp]    = *(const short8v*)(Wlo + (size_t)(n0+ar)*ldw + k0 + akp);
    *(short8v*)&Bs[1][ar+64][akp] = *(const short8v*)(Wlo + (size_t)(n0+ar+64)*ldw + k0 + akp);
    __syncthreads();
    const int l15 = lane & 15, kb8 = (lane>>4)*8;
    short8v a0[4], bh[4], bl[4];
    #pragma unroll
    for (int mt=0;mt<4;++mt) a0[mt] = *(const short8v*)&As[wm*64+mt*16+l15][kb8];
    #pragma unroll
    for (int nt=0;nt<4;++nt){
      bh[nt] = *(const short8v*)&Bs[0][wn*64+nt*16+l15][kb8];
      bl[nt] = *(const short8v*)&Bs[1][wn*64+nt*16+l15][kb8];
    }
    #pragma unroll
    for (int mt=0;mt<4;++mt)
      #pragma unroll
      for (int nt=0;nt<4;++nt){
        acc[mt][nt] = __builtin_amdgcn_mfma_f32_16x16x32_bf16(a0[mt], bh[nt], acc[mt][nt], 0,0,0);
        acc[mt][nt] = __builtin_amdgcn_mfma_f32_16x16x32_bf16(a0[mt], bl[nt], acc[mt][nt], 0,0,0);
      }
    __syncthreads();
  }
  const int l15 = lane & 15, rb = (lane>>4)*4;
  #pragma unroll
  for (int mt=0;mt<4;++mt){
    #pragma unroll
    for (int nt=0;nt<4;++nt){
      const int col = n0 + wn*64 + nt*16 + l15;
      const float bv = bias ? bias[col] : 0.f;
      #pragma unroll
      for (int i=0;i<4;++i){
        const size_t row = (size_t)m0 + wm*64 + mt*16 + rb + i;
        float v = acc[mt][nt][i] + bv;
        if (RELU) v = fmaxf(v, 0.f);
        st1(&C[row*ldc + col], v);
      }
    }
  }
}

// ---------- persistent k-split encoder LSTM, fast exchange ----------
// Same skeleton/ordering as r16 (proven correct); partial exchange now uses
// plain stores/loads bracketed by agent-scope fences, gathered in parallel.
__global__ __launch_bounds__(512) void lstm17(
   const bf16* __restrict__ Pf, const bf16* __restrict__ Pb,
   const bf16* __restrict__ Whf, const bf16* __restrict__ Whb,
   const int* __restrict__ lens, int lenDiv, int t0, int TC,
   bf16* __restrict__ out, int T, float* __restrict__ hc,
   float* __restrict__ part, int* __restrict__ arrive)
{
  const int q = blockIdx.x, b = blockIdx.y, dir = blockIdx.z;
  const int tid = threadIdx.x;
  const int g = dir*32 + b;
  int L = lens[b]; if (lenDiv==2) L = (L+1)>>1;
  int tcEnd = L - t0; if (tcEnd > TC) tcEnd = TC;
  const bf16* P = (dir ? Pb : Pf) + (size_t)b*TC*1024;
  const short* Wg = (const short*)(dir ? Whb : Whf);
  float* hcp = hc + (size_t)g*512;
  float* partg = part + (size_t)g*8192;     // [parity][q][1024]
  int* arr = arrive + g;

  __shared__ short wl[65536];               // [1024 rows][16 slots x 4 shorts], rotated
  __shared__ float hq[64];
  __shared__ float gs[1024];

  for (int pass=0; pass<16; ++pass){
    const int r = pass*64 + (tid>>3);
    const int li = tid & 7;
    const uint4 v = *(const uint4*)(Wg + (size_t)r*256 + q*64 + li*8);
    const int kk0 = li*2;
    *(uint2*)&wl[r*64 + (((kk0  ) + r)&15)*4] = make_uint2(v.x, v.y);
    *(uint2*)&wl[r*64 + (((kk0+1) + r)&15)*4] = make_uint2(v.z, v.w);
  }
  if (tid < 64) hq[tid] = hcp[q*64 + tid];
  float c = (tid < 64) ? hcp[256 + q*64 + tid] : 0.f;
  __syncthreads();

  for (int tc=0; tc<tcEnd; ++tc){
    // ---- k-quarter partial GEMV: rows tid and 512+tid ----
    const int r0 = tid, r1 = 512 + tid;
    float a0 = 0.f, a1 = 0.f;
    #pragma unroll
    for (int kk=0; kk<16; ++kk){
      const float4 h4 = *(const float4*)&hq[kk*4];
      const uint2 w0 = *(const uint2*)&wl[r0*64 + ((kk + r0)&15)*4];
      const uint2 w1 = *(const uint2*)&wl[r1*64 + ((kk + r1)&15)*4];
      a0 += bfu2f(w0.x<<16)*h4.x + bfu2f(w0.x&0xffff0000u)*h4.y
          + bfu2f(w0.y<<16)*h4.z + bfu2f(w0.y&0xffff0000u)*h4.w;
      a1 += bfu2f(w1.x<<16)*h4.x + bfu2f(w1.x&0xffff0000u)*h4.y
          + bfu2f(w1.y<<16)*h4.z + bfu2f(w1.y&0xffff0000u)*h4.w;
    }
    const int par = tc & 1;
    partg[par*4096 + q*1024 + r0] = a0;       // plain stores
    partg[par*4096 + q*1024 + r1] = a1;
    __threadfence();                          // release (agent scope)
    __syncthreads();
    if (tid == 0){
      atomicAdd(arr, 1);
      const int target = 4*(tc+1);
      while (atomicAdd(arr, 0) < target) __builtin_amdgcn_s_sleep(2);
    }
    __syncthreads();
    __threadfence();                          // acquire: invalidate stale caches
    // ---- parallel gather: all 512 threads sum 4 partials for 2 rows each ----
    {
      const float* pp = partg + par*4096;
      const float s0 = pp[r0] + pp[1024+r0] + pp[2048+r0] + pp[3072+r0];
      const float s1 = pp[r1] + pp[1024+r1] + pp[2048+r1] + pp[3072+r1];
      gs[r0] = s0 + b2f(P[(size_t)tc*1024 + r0]);
      gs[r1] = s1 + b2f(P[(size_t)tc*1024 + r1]);
    }
    __syncthreads();
    // ---- gate math for units [64q, 64q+64) ----
    if (tid < 64){
      const int unit = q*64 + tid;
      const float cn = sigf(gs[256+unit])*c + sigf(gs[unit])*tanhfast(gs[512+unit]);
      const float hn = sigf(gs[768+unit])*tanhfast(cn);
      c = cn;
      const int t = t0 + tc;
      const int srow = dir ? (L-1-t) : t;
      out[((size_t)b*T + srow)*512 + dir*256 + unit] = f2b(hn);
      hq[tid] = hn;
    }
    __syncthreads();
  }
  if (tcEnd > 0 && tid < 64){
    hcp[q*64 + tid] = hq[tid];
    hcp[256 + q*64 + tid] = c;
  }
}

// ---------- decoder phase A (r13-verbatim) ----------
__global__ __launch_bounds__(256) void dec_g(
  const bf16* __restrict__ Pd, const float* __restrict__ Wih,
  const float* __restrict__ Whh, const float* __restrict__ h_state,
  const float* __restrict__ ctx_state, float* __restrict__ g_buf, int s)
{
  const int b = blockIdx.x, jt = blockIdx.y, tid = threadIdx.x;
  const int j = jt*256 + tid;
  __shared__ float cs[512], hs[512];
  cs[tid] = ctx_state[b*512+tid]; cs[256+tid] = ctx_state[b*512+256+tid];
  hs[tid] = h_state[b*512+tid];   hs[256+tid] = h_state[b*512+256+tid];
  __syncthreads();
  float acc = b2f(Pd[((size_t)(s*32+b))*2048 + j]);
  const float* wc = Wih + (size_t)j*1024 + 512;
  const float* wh = Whh + (size_t)j*512;
  for (int k=0;k<512;k+=4){
    const float4 cv = *(const float4*)&cs[k];
    const float4 hv = *(const float4*)&hs[k];
    const float4 a  = *(const float4*)&wc[k];
    const float4 b4 = *(const float4*)&wh[k];
    acc += a.x*cv.x + a.y*cv.y + a.z*cv.z + a.w*cv.w;
    acc += b4.x*hv.x + b4.y*hv.y + b4.z*hv.z + b4.w*hv.w;
  }
  g_buf[b*2048 + j] = acc;
}

// ---------- decoder rest (r15-verbatim, 1024 threads) ----------
__global__ __launch_bounds__(1024) void dec_rest(
  const float* __restrict__ g_buf, const float* __restrict__ qW,
  const float* __restrict__ convW, const float* __restrict__ locW,
  const float* __restrict__ vW, const float* __restrict__ PM, const bf16* __restrict__ memB,
  const int* __restrict__ lens,
  float* __restrict__ h_state, float* __restrict__ c_state, float* __restrict__ ctx_state,
  float* __restrict__ aw_state, float* __restrict__ awc_state,
  float* __restrict__ hallctx, float* __restrict__ outA, int s)
{
  const int b = blockIdx.x, u = threadIdx.x;
  __shared__ float hsh[512], red[1024], aw_s[800], q_s[128], v_s[128];
  __shared__ float convW_s[1984], locW_s[4096];
  for (int i=u; i<1984; i+=1024) convW_s[i]=convW[i];
  for (int i=u; i<4096; i+=1024) locW_s[i]=locW[i];
  if (u<128) v_s[u]=vW[u];
  if (u<512){
    const float gi = g_buf[b*2048 + u],     gf = g_buf[b*2048+512+u];
    const float gg = g_buf[b*2048+1024+u],  go = g_buf[b*2048+1536+u];
    const float cn = sigf(gf)*c_state[b*512+u] + sigf(gi)*tanhfast(gg);
    const float hn = sigf(go)*tanhfast(cn);
    c_state[b*512+u]=cn; h_state[b*512+u]=hn; hsh[u]=hn;
    hallctx[((size_t)(s*32+b))*1024 + u] = hn;
  }
  __syncthreads();
  if (u<128){
    const float* wr = qW + u*512;
    float acc=0.f;
    for (int k=0;k<512;k+=4){
      const float4 w = *(const float4*)&wr[k];
      const float4 h = *(const float4*)&hsh[k];
      acc += w.x*h.x + w.y*h.y + w.z*h.z + w.w*h.w;
    }
    q_s[u]=acc;
  }
  __syncthreads();
  const int mlen = (lens[b]+1)>>1;
  const int t = u;
  float ex = 0.f;
  if (t < 800 && t < mlen){
    float convf[32];
    #pragma unroll
    for (int f=0;f<32;++f) convf[f]=0.f;
    for (int k=0;k<31;++k){
      const int pos = t-15+k;
      const bool ok = (pos>=0 && pos<800);
      const float a0 = ok ? aw_state[b*800+pos] : 0.f;
      const float a1 = ok ? awc_state[b*800+pos] : 0.f;
      #pragma unroll
      for (int f=0;f<32;++f)
        convf[f] += convW_s[(f*2+0)*31+k]*a0 + convW_s[(f*2+1)*31+k]*a1;
    }
    const float* pm = PM + ((size_t)b*800 + t)*128;
    float e = 0.f;
    for (int a=0;a<128;++a){
      float loc = 0.f;
      #pragma unroll
      for (int f=0;f<32;++f) loc += convf[f]*locW_s[a*32+f];
      e += v_s[a]*tanhfast(q_s[a]+loc+pm[a]);
    }
    ex = __expf(e);
  }
  red[u]=ex; __syncthreads();
  for (int st=512; st>0; st>>=1){
    if (u<st) red[u]+=red[u+st];
    __syncthreads();
  }
  const float invZ = 1.f/red[0];
  if (t<800){
    const float a0 = ex*invZ;
    aw_s[t]=a0; aw_state[b*800+t]=a0; awc_state[b*800+t]+=a0;
    outA[((size_t)b*161+s)*800+t] = a0;
  }
  __syncthreads();
  {
    const int half = u>>9, d = u&511;
    float acc=0.f;
    const int tb = half*400;
    for (int t2=tb; t2<tb+400; ++t2)
      acc += aw_s[t2]*b2f(memB[((size_t)b*800+t2)*512 + d]);
    red[half*512 + d] = acc;
  }
  __syncthreads();
  if (u<512){
    const float v = red[u] + red[512+u];
    ctx_state[b*512+u]=v;
    hallctx[((size_t)(s*32+b))*1024 + 512 + u] = v;
  }
}

// ---------- output scatters (r8-verbatim) ----------
__global__ void k_scat_h(const float* __restrict__ hid, float* __restrict__ outH){
  int i=blockIdx.x*256+threadIdx.x; if(i>=5152*512) return;
  int r=i>>9, d=i&511; int s=r>>5, b=r&31;
  outH[((size_t)b*161+s)*512 + d] = hid[i];
}
__global__ void k_scat_l(const float* __restrict__ lg, float* __restrict__ outL){
  int i=blockIdx.x*256+threadIdx.x; if(i>=5152*101) return;
  int r=i/101, n=i-r*101; int s=r>>5, b=r&31;
  outL[((size_t)b*161+s)*101 + n] = lg[r*128+n];
}

// ---------- host ----------
extern "C" void kernel_launch(void* const* d_in, const int* in_sizes, int n_in,
                              void* d_out, int out_size, void* d_ws, size_t ws_size,
                              hipStream_t stream)
{
  const float* mel    = (const float*)d_in[0];
  const int*   lens   = (const int*)  d_in[1];
  const float* dec_in = (const float*)d_in[2];
  const float* start  = (const float*)d_in[3];
  const float* l1fWih = (const float*)d_in[4];
  const float* l1fWhh = (const float*)d_in[5];
  const float* l1fb   = (const float*)d_in[6];
  const float* l1bWih = (const float*)d_in[7];
  const float* l1bWhh = (const float*)d_in[8];
  const float* l1bb   = (const float*)d_in[9];
  const float* l2fWih = (const float*)d_in[10];
  const float* l2fWhh = (const float*)d_in[11];
  const float* l2fb   = (const float*)d_in[12];
  const float* l2bWih = (const float*)d_in[13];
  const float* l2bWhh = (const float*)d_in[14];
  const float* l2bb   = (const float*)d_in[15];
  const float* decWih = (const float*)d_in[16];
  const float* decWhh = (const float*)d_in[17];
  const float* decb   = (const float*)d_in[18];
  const float* qW     = (const float*)d_in[19];
  const float* mW     = (const float*)d_in[20];
  const float* convW  = (const float*)d_in[21];
  const float* locW   = (const float*)d_in[22];
  const float* vW     = (const float*)d_in[23];
  const float* phW    = (const float*)d_in[24];
  const float* phb    = (const float*)d_in[25];
  const float* psW    = (const float*)d_in[26];
  const float* psb    = (const float*)d_in[27];
  (void)in_sizes; (void)n_in; (void)out_size; (void)ws_size;

  char* wsp = (char*)d_ws;
  size_t off = 0;
  auto alloc = [&](size_t bytes)->char*{
    char* p = wsp + off; off += (bytes + 255) & ~(size_t)255; return p;
  };

  // ---- persistent small buffers ----
  float* stateF   = (float*)alloc((size_t)100352*4);
  float* h_state  = stateF;
  float* c_state  = stateF + 16384;
  float* ctx_state= stateF + 32768;
  float* aw_state = stateF + 49152;
  float* awc_state= stateF + 74752;
  float* hc_enc   = (float*)alloc((size_t)32768*4);
  float* g_buf    = (float*)alloc((size_t)65536*4);
  float* psW_p    = (float*)alloc((size_t)65536*4);
  float* psb_p    = (float*)alloc((size_t)128*4);
  float* part     = (float*)alloc((size_t)524288*4);   // [64 g][2 par][4 q][1024]
  int*   arrive   = (int*)  alloc((size_t)64*4);
  bf16*  whh1f    = (bf16*)alloc((size_t)262144*2);    // plain [1024,256] bf16
  bf16*  whh1b    = (bf16*)alloc((size_t)262144*2);
  bf16*  whh2f    = (bf16*)alloc((size_t)262144*2);
  bf16*  whh2b    = (bf16*)alloc((size_t)262144*2);
  bf16*  w_m_h    = (bf16*)alloc((size_t)65536*2);
  bf16*  w_m_l    = (bf16*)alloc((size_t)65536*2);
  bf16*  w_l1f_h  = (bf16*)alloc((size_t)98304*2);
  bf16*  w_l1f_l  = (bf16*)alloc((size_t)98304*2);
  bf16*  w_l1b_h  = (bf16*)alloc((size_t)98304*2);
  bf16*  w_l1b_l  = (bf16*)alloc((size_t)98304*2);

  // ---- arenas (r15 layout) ----
  char* R_X = alloc((size_t)10747904);
  bf16*  xTb   = (bf16*)R_X;
  bf16*  w_l2f_h = (bf16*)R_X;
  bf16*  w_l2f_l = (bf16*)(R_X + 2097152);
  bf16*  w_l2b_h = (bf16*)(R_X + 4194304);
  bf16*  w_l2b_l = (bf16*)(R_X + 6291456);
  bf16*  dseqB = (bf16*)R_X;
  bf16*  w_pd_h = (bf16*)(R_X + 5505024);
  bf16*  w_pd_l = (bf16*)(R_X + 7602176);
  float* hid  = (float*)R_X;
  char* R_P = alloc((size_t)26214400);
  bf16* Pchf = (bf16*)R_P;
  bf16* Pchb = (bf16*)(R_P + 10485760);
  bf16* Pd   = (bf16*)R_P;
  float* logitb = (float*)(R_P + 21495808);
  char* R_O = alloc((size_t)52428800);
  bf16*  out1    = (bf16*)R_O;
  float* PM      = (float*)R_O;
  float* hallctx = (float*)(R_O + 13107200);
  char* R_M = alloc((size_t)26214400);
  bf16*  memB = (bf16*)R_M;
  // peak ws ~= 123 MB

  float* outF = (float*)d_out;            // FLOAT32 OUTPUT
  float* outH = outF;                     // [32,161,512]
  float* outL = outF + 2637824;           // [32,161,101]
  float* outA = outF + 3158176;           // [32,161,800]

  // ---- init / weight prep ----
  k_zero_f<<<392,256,0,stream>>>(stateF, 100352);
  k_zero_f<<<128,256,0,stream>>>(hc_enc, 32768);
  k_xT96b<<<19200,256,0,stream>>>(mel, xTb);
  k_padW96b2<<<384,256,0,stream>>>(l1fWih, w_l1f_h, w_l1f_l);
  k_padW96b2<<<384,256,0,stream>>>(l1bWih, w_l1b_h, w_l1b_l);
  k_cvt<<<1024,256,0,stream>>>(l1fWhh, whh1f, 262144);
  k_cvt<<<1024,256,0,stream>>>(l1bWhh, whh1b, 262144);
  k_cvt<<<1024,256,0,stream>>>(l2fWhh, whh2f, 262144);
  k_cvt<<<1024,256,0,stream>>>(l2bWhh, whh2b, 262144);
  k_cvt2<<<256,256,0,stream>>>(mW, w_m_h, w_m_l, 65536);
  k_psW<<<257,256,0,stream>>>(psW, psb, psW_p, psb_p);
  k_zero_b<<<2048,256,0,stream>>>(out1, 26214400);
  k_zero_b<<<2048,256,0,stream>>>(memB, 13107200);

  // ---- encoder layer 1: 10 chunks x 160 steps ----
  for (int c=0;c<10;++c){
    const int t0 = c*160;
    gemmM<false,bf16><<<dim3(8,40),256,0,stream>>>(xTb,96, 1600,160,t0, lens,1,0,
        (const short*)w_l1f_h,(const short*)w_l1f_l,96, l1fb, Pchf,1024, 96);
    gemmM<false,bf16><<<dim3(8,40),256,0,stream>>>(xTb,96, 1600,160,t0, lens,1,1,
        (const short*)w_l1b_h,(const short*)w_l1b_l,96, l1bb, Pchb,1024, 96);
    k_zero_f<<<1,64,0,stream>>>((float*)arrive, 64);
    lstm17<<<dim3(4,32,2),512,0,stream>>>(Pchf,Pchb, whh1f,whh1b, lens,1, t0,160,
                                          out1, 1600, hc_enc, part, arrive);
  }

  // ---- l2 weight hi/lo planes into R_X (xTb dead) ----
  k_cvt2<<<4096,256,0,stream>>>(l2fWih, w_l2f_h, w_l2f_l, 1048576);
  k_cvt2<<<4096,256,0,stream>>>(l2bWih, w_l2b_h, w_l2b_l, 1048576);

  // ---- encoder layer 2: 5 chunks x 160 steps ----
  k_zero_f<<<128,256,0,stream>>>(hc_enc, 32768);
  for (int c=0;c<5;++c){
    const int t0 = c*160;
    gemmM<false,bf16><<<dim3(8,40),256,0,stream>>>(out1,1024, 800,160,t0, lens,2,0,
        (const short*)w_l2f_h,(const short*)w_l2f_l,1024, l2fb, Pchf,1024, 1024);
    gemmM<false,bf16><<<dim3(8,40),256,0,stream>>>(out1,1024, 800,160,t0, lens,2,1,
        (const short*)w_l2b_h,(const short*)w_l2b_l,1024, l2bb, Pchb,1024, 1024);
    k_zero_f<<<1,64,0,stream>>>((float*)arrive, 64);
    lstm17<<<dim3(4,32,2),512,0,stream>>>(Pchf,Pchb, whh2f,whh2b, lens,2, t0,160,
                                          memB, 800, hc_enc, part, arrive);
  }

  // ---- decoder precompute ----
  gemmM<false,float><<<dim3(1,200),256,0,stream>>>(memB,512, 0,0,0, nullptr,0,0,
      (const short*)w_m_h,(const short*)w_m_l,512, (const float*)nullptr, PM,128, 512);
  k_zero_b<<<2048,256,0,stream>>>(dseqB, 2686976);
  k_dseqb<<<10304,256,0,stream>>>(start, dec_in, dseqB);
  k_wpd<<<4096,256,0,stream>>>(decWih, w_pd_h, w_pd_l);
  gemmM<false,bf16><<<dim3(16,41),256,0,stream>>>(dseqB,512, 0,0,0, nullptr,0,0,
      (const short*)w_pd_h,(const short*)w_pd_l,512, decb, Pd,2048, 512);
  k_zero_f<<<2048,256,0,stream>>>(hallctx, 5308416);

  // ---- decoder: 161 steps x 2 kernels (r15) ----
  for (int s=0; s<161; ++s){
    dec_g<<<dim3(32,8),256,0,stream>>>(Pd, decWih, decWhh, h_state, ctx_state, g_buf, s);
    dec_rest<<<32,1024,0,stream>>>(g_buf, qW, convW, locW, vW, PM, memB, lens,
                                   h_state, c_state, ctx_state, aw_state, awc_state,
                                   hallctx, outA, s);
  }

  // ---- deferred projections + scatter ----
  gemm64<true ,float,float><<<dim3(8,81),256,0,stream>>>(hallctx,1024, 0,0,0, nullptr,0,0,
                                                phW,1024, phb, hid,512, 1024);
  gemm64<false,float,float><<<dim3(2,81),256,0,stream>>>(hid,512, 0,0,0, nullptr,0,0,
                                                psW_p,512, psb_p, logitb,128, 512);
  k_scat_h<<<10304,256,0,stream>>>(hid, outH);
  k_scat_l<<<2033,256,0,stream>>>(logitb, outL);
}

// Round 18
// 37942.001 us; speedup vs baseline: 4.3503x; 4.3503x over previous
//
#include <hip/hip_runtime.h>
#include <hip/hip_bf16.h>

typedef __hip_bfloat16 bf16;
typedef __attribute__((ext_vector_type(8))) short short8v;
typedef __attribute__((ext_vector_type(4))) float float4v;
#define DEVINL __device__ __forceinline__

DEVINL float bfu2f(unsigned int u){ union{unsigned int u; float f;} c; c.u=u; return c.f; }
DEVINL float b2f(bf16 v){ return __bfloat162float(v); }
DEVINL bf16  f2b(float f){ return __float2bfloat16(f); }
DEVINL float sigf(float x){ return 1.f/(1.f+__expf(-x)); }
DEVINL float tanhfast(float x){
  float t=__expf(-2.f*fabsf(x));
  float r=(1.f-t)/(1.f+t);
  return copysignf(r,x);
}
DEVINL void hilo(float x, short& h, short& l){
  bf16 hb = __float2bfloat16(x);
  bf16 lb = __float2bfloat16(x - __bfloat162float(hb));
  h = *(short*)&hb; l = *(short*)&lb;
}
DEVINL void ld4(const bf16* __restrict__ p, float* d){
  uint2 v = *reinterpret_cast<const uint2*>(p);
  d[0]=bfu2f(v.x<<16); d[1]=bfu2f(v.x&0xffff0000u);
  d[2]=bfu2f(v.y<<16); d[3]=bfu2f(v.y&0xffff0000u);
}
DEVINL void ld4(const float* __restrict__ p, float* d){
  float4 v = *reinterpret_cast<const float4*>(p);
  d[0]=v.x; d[1]=v.y; d[2]=v.z; d[3]=v.w;
}
DEVINL void st1(bf16* p, float v){ *p = f2b(v); }
DEVINL void st1(float* p, float v){ *p = v; }

// ---------- zero / prep ----------
__global__ void k_zero_f(float* p, long n){
  long i=(long)blockIdx.x*256+threadIdx.x, st=(long)gridDim.x*256;
  for(;i<n;i+=st) p[i]=0.f;
}
__global__ void k_zero_b(bf16* p, long n){
  long i=(long)blockIdx.x*256+threadIdx.x, st=(long)gridDim.x*256;
  for(;i<n;i+=st) p[i]=f2b(0.f);
}
// xTb[b*1600+t][d<96] = mel[b][d][t] (d>=80 -> 0), bf16
__global__ void k_xT96b(const float* __restrict__ mel, bf16* __restrict__ xT){
  int i = blockIdx.x*256+threadIdx.x; if(i>=51200*96) return;
  int m = i/96, d = i - m*96; int b = m/1600, t = m - b*1600;
  xT[i] = f2b((d<80)? mel[((size_t)b*80 + d)*1600 + t] : 0.f);
}
// [1024,80] f32 -> [1024,96] (hi,lo) bf16 zero-padded
__global__ void k_padW96b2(const float* __restrict__ W, bf16* __restrict__ hi,
                           bf16* __restrict__ lo){
  int i = blockIdx.x*256+threadIdx.x; if(i>=1024*96) return;
  int j=i/96, d=i-j*96;
  float x = (d<80)? W[j*80+d] : 0.f;
  short h,l; hilo(x,h,l);
  hi[i]=*(bf16*)&h; lo[i]=*(bf16*)&l;
}
// f32 -> (hi,lo) bf16 split (contiguous)
__global__ void k_cvt2(const float* __restrict__ W, bf16* __restrict__ hi,
                       bf16* __restrict__ lo, int n){
  int i=blockIdx.x*256+threadIdx.x; if(i>=n) return;
  short h,l; hilo(W[i], h, l);
  hi[i]=*(bf16*)&h; lo[i]=*(bf16*)&l;
}
// Whh [1024,256] f32 -> bf16 interleaved il[(kc*1024 + j)*8 + kk] (r13-verified)
__global__ void k_whh_il8(const float* __restrict__ W, bf16* __restrict__ il){
  int i = blockIdx.x*256+threadIdx.x; if(i>=262144) return;
  int kk = i&7; int j = (i>>3)&1023; int kc = i>>13;
  il[i] = f2b(W[j*256 + kc*8 + kk]);
}
// ps_W [101,512] -> [128,512] f32 zero-padded rows; ps_b -> [128]
__global__ void k_psW(const float* __restrict__ W, const float* __restrict__ bsrc,
                      float* __restrict__ Wp, float* __restrict__ bp){
  int i=blockIdx.x*256+threadIdx.x;
  if(i<128*512){ int n=i/512,k=i-n*512; Wp[i] = (n<101)? W[n*512+k] : 0.f; }
  else if(i<128*512+128){ int n=i-128*512; bp[n]=(n<101)? bsrc[n]:0.f; }
}
// dseqB[r=s*32+b][e] bf16 (rows < 5152; pad rows pre-zeroed)
__global__ void k_dseqb(const float* __restrict__ start, const float* __restrict__ dec_in,
                        bf16* __restrict__ dseq){
  int i=blockIdx.x*256+threadIdx.x; if(i>=5152*512) return;
  int r=i/512, e=i-r*512; int s=r/32, b=r-s*32;
  dseq[i] = f2b((s==0)? start[b*512+e] : dec_in[(size_t)b*81920 + e*160 + (s-1)]);
}
// w_pd = decWih[:, 0:512] hi/lo  ([2048,512])
__global__ void k_wpd(const float* __restrict__ Wih, bf16* __restrict__ hi,
                      bf16* __restrict__ lo){
  int i=blockIdx.x*256+threadIdx.x; if(i>=2048*512) return;
  int j=i>>9, k=i&511;
  short h,l; hilo(Wih[(size_t)j*1024 + k], h, l);
  hi[i]=*(bf16*)&h; lo[i]=*(bf16*)&l;
}

// ---------- scalar GEMM 64x64 (r8-verbatim; ph/ps only) ----------
template<bool RELU, typename TA, typename TCO>
__global__ __launch_bounds__(256) void gemm64(
    const TA* __restrict__ A, int lda, int T, int TC, int t0,
    const int* __restrict__ lens, int lenDiv, int rev,
    const float* __restrict__ W, int ldw,
    const float* __restrict__ bias,
    TCO* __restrict__ C, int ldc, int K)
{
  __shared__ float As[16][64];
  __shared__ float Ws[16][64];
  const int tid = threadIdx.x;
  const int n0 = blockIdx.x*64, m0 = blockIdx.y*64;
  const int tx = tid & 15, ty = tid >> 4;
  const int r = tid >> 2, c4 = (tid & 3) * 4;
  const int m = m0 + r;
  size_t arow;
  if (lens){
    int b = m / TC, tc = m - b*TC, t = t0 + tc;
    if (rev){
      int L = lens[b]; if (lenDiv==2) L=(L+1)>>1;
      t = L-1-t; if (t<0) t=0;
    }
    arow = (size_t)b*T + t;
  } else arow = (size_t)m;
  float acc[4][4] = {{0.f}};
  for (int k0=0; k0<K; k0+=16){
    float av[4];
    ld4(A + arow*lda + k0 + c4, av);
    const float4 wv = *reinterpret_cast<const float4*>(&W[(size_t)(n0+r)*ldw + k0 + c4]);
    As[c4+0][r] = av[0]; As[c4+1][r] = av[1]; As[c4+2][r] = av[2]; As[c4+3][r] = av[3];
    Ws[c4+0][r] = wv.x; Ws[c4+1][r]=wv.y; Ws[c4+2][r]=wv.z; Ws[c4+3][r]=wv.w;
    __syncthreads();
    #pragma unroll
    for(int k=0;k<16;k++){
      const float4 a = *reinterpret_cast<const float4*>(&As[k][ty*4]);
      const float4 w = *reinterpret_cast<const float4*>(&Ws[k][tx*4]);
      acc[0][0] += a.x*w.x; acc[0][1] += a.x*w.y; acc[0][2] += a.x*w.z; acc[0][3] += a.x*w.w;
      acc[1][0] += a.y*w.x; acc[1][1] += a.y*w.y; acc[1][2] += a.y*w.z; acc[1][3] += a.y*w.w;
      acc[2][0] += a.z*w.x; acc[2][1] += a.z*w.y; acc[2][2] += a.z*w.z; acc[2][3] += a.z*w.w;
      acc[3][0] += a.w*w.x; acc[3][1] += a.w*w.y; acc[3][2] += a.w*w.z; acc[3][3] += a.w*w.w;
    }
    __syncthreads();
  }
  #pragma unroll
  for(int i=0;i<4;i++){
    const size_t row = (size_t)m0 + ty*4 + i;
    #pragma unroll
    for(int j=0;j<4;j++){
      const int col = n0 + tx*4 + j;
      float v = acc[i][j] + (bias ? bias[col] : 0.f);
      if (RELU) v = fmaxf(v, 0.f);
      st1(&C[row*ldc + col], v);
    }
  }
}

// ---------- MFMA GEMM (bf16 A, hi/lo weights, 2 passes) — r12/r13-verified verbatim ----------
template<bool RELU, typename TCO>
__global__ __launch_bounds__(256) void gemmM(
    const bf16* __restrict__ A, int lda, int T, int TC, int t0,
    const int* __restrict__ lens, int lenDiv, int rev,
    const short* __restrict__ Whi, const short* __restrict__ Wlo, int ldw,
    const float* __restrict__ bias,
    TCO* __restrict__ C, int ldc, int K)
{
  __shared__ short As[128][40];
  __shared__ short Bs[2][128][40];
  const int tid = threadIdx.x;
  const int lane = tid & 63, wave = tid >> 6;
  const int wm = wave >> 1, wn = wave & 1;
  const int n0 = blockIdx.x*128, m0 = blockIdx.y*128;

  auto arow_of = [&](int m)->size_t{
    if (lens){
      int b = m / TC, tc = m - b*TC, t = t0 + tc;
      if (rev){ int L=lens[b]; if(lenDiv==2) L=(L+1)>>1; t=L-1-t; if(t<0)t=0; }
      return (size_t)b*T + t;
    }
    return (size_t)m;
  };

  float4v acc[4][4];
  #pragma unroll
  for (int i=0;i<4;++i)
    #pragma unroll
    for (int j=0;j<4;++j) acc[i][j] = (float4v){0.f,0.f,0.f,0.f};

  const int ar = tid>>2, akp = (tid&3)*8;
  const size_t arow0 = arow_of(m0 + ar), arow1 = arow_of(m0 + ar + 64);
  const short* Ash = (const short*)A;

  for (int k0=0; k0<K; k0+=32){
    *(short8v*)&As[ar][akp]    = *(const short8v*)(Ash + arow0*lda + k0 + akp);
    *(short8v*)&As[ar+64][akp] = *(const short8v*)(Ash + arow1*lda + k0 + akp);
    *(short8v*)&Bs[0][ar][akp]    = *(const short8v*)(Whi + (size_t)(n0+ar)*ldw + k0 + akp);
    *(short8v*)&Bs[0][ar+64][akp] = *(const short8v*)(Whi + (size_t)(n0+ar+64)*ldw + k0 + akp);
    *(short8v*)&Bs[1][ar][akp]    = *(const short8v*)(Wlo + (size_t)(n0+ar)*ldw + k0 + akp);
    *(short8v*)&Bs[1][ar+64][akp] = *(const short8v*)(Wlo + (size_t)(n0+ar+64)*ldw + k0 + akp);
    __syncthreads();
    const int l15 = lane & 15, kb8 = (lane>>4)*8;
    short8v a0[4], bh[4], bl[4];
    #pragma unroll
    for (int mt=0;mt<4;++mt) a0[mt] = *(const short8v*)&As[wm*64+mt*16+l15][kb8];
    #pragma unroll
    for (int nt=0;nt<4;++nt){
      bh[nt] = *(const short8v*)&Bs[0][wn*64+nt*16+l15][kb8];
      bl[nt] = *(const short8v*)&Bs[1][wn*64+nt*16+l15][kb8];
    }
    #pragma unroll
    for (int mt=0;mt<4;++mt)
      #pragma unroll
      for (int nt=0;nt<4;++nt){
        acc[mt][nt] = __builtin_amdgcn_mfma_f32_16x16x32_bf16(a0[mt], bh[nt], acc[mt][nt], 0,0,0);
        acc[mt][nt] = __builtin_amdgcn_mfma_f32_16x16x32_bf16(a0[mt], bl[nt], acc[mt][nt], 0,0,0);
      }
    __syncthreads();
  }
  const int l15 = lane & 15, rb = (lane>>4)*4;
  #pragma unroll
  for (int mt=0;mt<4;++mt){
    #pragma unroll
    for (int nt=0;nt<4;++nt){
      const int col = n0 + wn*64 + nt*16 + l15;
      const float bv = bias ? bias[col] : 0.f;
      #pragma unroll
      for (int i=0;i<4;++i){
        const size_t row = (size_t)m0 + wm*64 + mt*16 + rb + i;
        float v = acc[mt][nt][i] + bv;
        if (RELU) v = fmaxf(v, 0.f);
        st1(&C[row*ldc + col], v);
      }
    }
  }
}

// ---------- encoder LSTM chunk (r13-verbatim, coalesced weights) ----------
__global__ __launch_bounds__(1024) void lstm8(
   const bf16* __restrict__ Pf, const bf16* __restrict__ Pb,
   const bf16* __restrict__ Whf, const bf16* __restrict__ Whb,
   const int* __restrict__ lens, int lenDiv, int t0, int TC,
   bf16* __restrict__ out, int T, float* __restrict__ hc)
{
  const int b = blockIdx.x, dir = blockIdx.y, j = threadIdx.x;
  int L = lens[b]; if (lenDiv==2) L = (L+1)>>1;
  const bf16* P  = (dir ? Pb : Pf) + (size_t)b*TC*1024;
  const bf16* wil = (dir ? Whb : Whf) + (size_t)j*8;
  float* hcp = hc + (size_t)(dir*32+b)*512;
  __shared__ float hs[256];
  __shared__ float gs[1024];
  if (j<256) hs[j] = hcp[j];
  float c = (j<256) ? hcp[256+j] : 0.f;
  __syncthreads();
  int tcEnd = L - t0; if (tcEnd > TC) tcEnd = TC;
  for (int tc=0; tc<tcEnd; ++tc){
    float acc = b2f(P[(size_t)tc*1024 + j]);
    #pragma unroll 8
    for (int kc=0; kc<32; ++kc){
      const uint4 wv = *reinterpret_cast<const uint4*>(wil + (size_t)kc*8192);
      const int k = kc*8;
      acc += bfu2f(wv.x<<16)*hs[k]   + bfu2f(wv.x&0xffff0000u)*hs[k+1]
           + bfu2f(wv.y<<16)*hs[k+2] + bfu2f(wv.y&0xffff0000u)*hs[k+3]
           + bfu2f(wv.z<<16)*hs[k+4] + bfu2f(wv.z&0xffff0000u)*hs[k+5]
           + bfu2f(wv.w<<16)*hs[k+6] + bfu2f(wv.w&0xffff0000u)*hs[k+7];
    }
    gs[j] = acc;
    __syncthreads();
    if (j<256){
      const float cn = sigf(gs[256+j])*c + sigf(gs[j])*tanhfast(gs[512+j]);
      const float hn = sigf(gs[768+j])*tanhfast(cn);
      c = cn;
      const int t = t0+tc;
      const int srow = dir ? (L-1-t) : t;
      out[((size_t)b*T + srow)*512 + dir*256 + j] = f2b(hn);
      hs[j] = hn;
    }
    __syncthreads();
  }
  if (j<256){ hcp[j]=hs[j]; hcp[256+j]=c; }
}

// ---------- decoder phase A (r13-verbatim): g = Pd[s] + ctx@Wih[:,512:]^T + h@Whh^T ----------
__global__ __launch_bounds__(256) void dec_g(
  const bf16* __restrict__ Pd, const float* __restrict__ Wih,
  const float* __restrict__ Whh, const float* __restrict__ h_state,
  const float* __restrict__ ctx_state, float* __restrict__ g_buf, int s)
{
  const int b = blockIdx.x, jt = blockIdx.y, tid = threadIdx.x;
  const int j = jt*256 + tid;
  __shared__ float cs[512], hs[512];
  cs[tid] = ctx_state[b*512+tid]; cs[256+tid] = ctx_state[b*512+256+tid];
  hs[tid] = h_state[b*512+tid];   hs[256+tid] = h_state[b*512+256+tid];
  __syncthreads();
  float acc = b2f(Pd[((size_t)(s*32+b))*2048 + j]);
  const float* wc = Wih + (size_t)j*1024 + 512;
  const float* wh = Whh + (size_t)j*512;
  for (int k=0;k<512;k+=4){
    const float4 cv = *(const float4*)&cs[k];
    const float4 hv = *(const float4*)&hs[k];
    const float4 a  = *(const float4*)&wc[k];
    const float4 b4 = *(const float4*)&wh[k];
    acc += a.x*cv.x + a.y*cv.y + a.z*cv.z + a.w*cv.w;
    acc += b4.x*hv.x + b4.y*hv.y + b4.z*hv.z + b4.w*hv.w;
  }
  g_buf[b*2048 + j] = acc;
}

// ---------- decoder rest (1024 threads: 1 energy column per thread) ----------
__global__ __launch_bounds__(1024) void dec_rest(
  const float* __restrict__ g_buf, const float* __restrict__ qW,
  const float* __restrict__ convW, const float* __restrict__ locW,
  const float* __restrict__ vW, const float* __restrict__ PM, const bf16* __restrict__ memB,
  const int* __restrict__ lens,
  float* __restrict__ h_state, float* __restrict__ c_state, float* __restrict__ ctx_state,
  float* __restrict__ aw_state, float* __restrict__ awc_state,
  float* __restrict__ hallctx, float* __restrict__ outA, int s)
{
  const int b = blockIdx.x, u = threadIdx.x;
  __shared__ float hsh[512], red[1024], aw_s[800], q_s[128], v_s[128];
  __shared__ float convW_s[1984], locW_s[4096];
  for (int i=u; i<1984; i+=1024) convW_s[i]=convW[i];
  for (int i=u; i<4096; i+=1024) locW_s[i]=locW[i];
  if (u<128) v_s[u]=vW[u];
  if (u<512){
    const float gi = g_buf[b*2048 + u],     gf = g_buf[b*2048+512+u];
    const float gg = g_buf[b*2048+1024+u],  go = g_buf[b*2048+1536+u];
    const float cn = sigf(gf)*c_state[b*512+u] + sigf(gi)*tanhfast(gg);
    const float hn = sigf(go)*tanhfast(cn);
    c_state[b*512+u]=cn; h_state[b*512+u]=hn; hsh[u]=hn;
    hallctx[((size_t)(s*32+b))*1024 + u] = hn;
  }
  __syncthreads();
  if (u<128){
    const float* wr = qW + u*512;
    float acc=0.f;
    for (int k=0;k<512;k+=4){
      const float4 w = *(const float4*)&wr[k];
      const float4 h = *(const float4*)&hsh[k];
      acc += w.x*h.x + w.y*h.y + w.z*h.z + w.w*h.w;
    }
    q_s[u]=acc;
  }
  __syncthreads();
  const int mlen = (lens[b]+1)>>1;
  const int t = u;
  float ex = 0.f;
  if (t < 800 && t < mlen){
    float convf[32];
    #pragma unroll
    for (int f=0;f<32;++f) convf[f]=0.f;
    for (int k=0;k<31;++k){
      const int pos = t-15+k;
      const bool ok = (pos>=0 && pos<800);
      const float a0 = ok ? aw_state[b*800+pos] : 0.f;
      const float a1 = ok ? awc_state[b*800+pos] : 0.f;
      #pragma unroll
      for (int f=0;f<32;++f)
        convf[f] += convW_s[(f*2+0)*31+k]*a0 + convW_s[(f*2+1)*31+k]*a1;
    }
    const float* pm = PM + ((size_t)b*800 + t)*128;
    float e = 0.f;
    for (int a=0;a<128;++a){
      float loc = 0.f;
      #pragma unroll
      for (int f=0;f<32;++f) loc += convf[f]*locW_s[a*32+f];
      e += v_s[a]*tanhfast(q_s[a]+loc+pm[a]);
    }
    ex = __expf(e);
  }
  red[u]=ex; __syncthreads();
  for (int st=512; st>0; st>>=1){
    if (u<st) red[u]+=red[u+st];
    __syncthreads();
  }
  const float invZ = 1.f/red[0];
  if (t<800){
    const float a0 = ex*invZ;
    aw_s[t]=a0; aw_state[b*800+t]=a0; awc_state[b*800+t]+=a0;
    outA[((size_t)b*161+s)*800+t] = a0;
  }
  __syncthreads();
  {
    const int half = u>>9, d = u&511;
    float acc=0.f;
    const int tb = half*400;
    for (int t2=tb; t2<tb+400; ++t2)
      acc += aw_s[t2]*b2f(memB[((size_t)b*800+t2)*512 + d]);
    red[half*512 + d] = acc;
  }
  __syncthreads();
  if (u<512){
    const float v = red[u] + red[512+u];
    ctx_state[b*512+u]=v;
    hallctx[((size_t)(s*32+b))*1024 + 512 + u] = v;
  }
}

// ---------- output scatters (r8-verbatim) ----------
__global__ void k_scat_h(const float* __restrict__ hid, float* __restrict__ outH){
  int i=blockIdx.x*256+threadIdx.x; if(i>=5152*512) return;
  int r=i>>9, d=i&511; int s=r>>5, b=r&31;
  outH[((size_t)b*161+s)*512 + d] = hid[i];
}
__global__ void k_scat_l(const float* __restrict__ lg, float* __restrict__ outL){
  int i=blockIdx.x*256+threadIdx.x; if(i>=5152*101) return;
  int r=i/101, n=i-r*101; int s=r>>5, b=r&31;
  outL[((size_t)b*161+s)*101 + n] = lg[r*128+n];
}

// ---------- host ----------
extern "C" void kernel_launch(void* const* d_in, const int* in_sizes, int n_in,
                              void* d_out, int out_size, void* d_ws, size_t ws_size,
                              hipStream_t stream)
{
  const float* mel    = (const float*)d_in[0];
  const int*   lens   = (const int*)  d_in[1];
  const float* dec_in = (const float*)d_in[2];
  const float* start  = (const float*)d_in[3];
  const float* l1fWih = (const float*)d_in[4];
  const float* l1fWhh = (const float*)d_in[5];
  const float* l1fb   = (const float*)d_in[6];
  const float* l1bWih = (const float*)d_in[7];
  const float* l1bWhh = (const float*)d_in[8];
  const float* l1bb   = (const float*)d_in[9];
  const float* l2fWih = (const float*)d_in[10];
  const float* l2fWhh = (const float*)d_in[11];
  const float* l2fb   = (const float*)d_in[12];
  const float* l2bWih = (const float*)d_in[13];
  const float* l2bWhh = (const float*)d_in[14];
  const float* l2bb   = (const float*)d_in[15];
  const float* decWih = (const float*)d_in[16];
  const float* decWhh = (const float*)d_in[17];
  const float* decb   = (const float*)d_in[18];
  const float* qW     = (const float*)d_in[19];
  const float* mW     = (const float*)d_in[20];
  const float* convW  = (const float*)d_in[21];
  const float* locW   = (const float*)d_in[22];
  const float* vW     = (const float*)d_in[23];
  const float* phW    = (const float*)d_in[24];
  const float* phb    = (const float*)d_in[25];
  const float* psW    = (const float*)d_in[26];
  const float* psb    = (const float*)d_in[27];
  (void)in_sizes; (void)n_in; (void)out_size; (void)ws_size;

  char* wsp = (char*)d_ws;
  size_t off = 0;
  auto alloc = [&](size_t bytes)->char*{
    char* p = wsp + off; off += (bytes + 255) & ~(size_t)255; return p;
  };

  // ---- persistent small buffers ----
  float* stateF   = (float*)alloc((size_t)100352*4);
  float* h_state  = stateF;
  float* c_state  = stateF + 16384;
  float* ctx_state= stateF + 32768;
  float* aw_state = stateF + 49152;
  float* awc_state= stateF + 74752;
  float* hc_enc   = (float*)alloc((size_t)32768*4);
  float* g_buf    = (float*)alloc((size_t)65536*4);
  float* psW_p    = (float*)alloc((size_t)65536*4);
  float* psb_p    = (float*)alloc((size_t)128*4);
  bf16*  whh1f    = (bf16*)alloc((size_t)262144*2);
  bf16*  whh1b    = (bf16*)alloc((size_t)262144*2);
  bf16*  whh2f    = (bf16*)alloc((size_t)262144*2);
  bf16*  whh2b    = (bf16*)alloc((size_t)262144*2);
  bf16*  w_m_h    = (bf16*)alloc((size_t)65536*2);
  bf16*  w_m_l    = (bf16*)alloc((size_t)65536*2);
  bf16*  w_l1f_h  = (bf16*)alloc((size_t)98304*2);
  bf16*  w_l1f_l  = (bf16*)alloc((size_t)98304*2);
  bf16*  w_l1b_h  = (bf16*)alloc((size_t)98304*2);
  bf16*  w_l1b_l  = (bf16*)alloc((size_t)98304*2);

  // ---- arenas (r15 layout) ----
  char* R_X = alloc((size_t)10747904);
  bf16*  xTb   = (bf16*)R_X;
  bf16*  w_l2f_h = (bf16*)R_X;
  bf16*  w_l2f_l = (bf16*)(R_X + 2097152);
  bf16*  w_l2b_h = (bf16*)(R_X + 4194304);
  bf16*  w_l2b_l = (bf16*)(R_X + 6291456);
  bf16*  dseqB = (bf16*)R_X;
  bf16*  w_pd_h = (bf16*)(R_X + 5505024);
  bf16*  w_pd_l = (bf16*)(R_X + 7602176);
  float* hid  = (float*)R_X;
  char* R_P = alloc((size_t)26214400);
  bf16* Pchf = (bf16*)R_P;
  bf16* Pchb = (bf16*)(R_P + 10485760);
  bf16* Pd   = (bf16*)R_P;
  float* logitb = (float*)(R_P + 21495808);
  char* R_O = alloc((size_t)52428800);
  bf16*  out1    = (bf16*)R_O;
  float* PM      = (float*)R_O;
  float* hallctx = (float*)(R_O + 13107200);
  char* R_M = alloc((size_t)26214400);
  bf16*  memB = (bf16*)R_M;
  // peak ws ~= 121 MB

  float* outF = (float*)d_out;            // FLOAT32 OUTPUT
  float* outH = outF;                     // [32,161,512]
  float* outL = outF + 2637824;           // [32,161,101]
  float* outA = outF + 3158176;           // [32,161,800]

  // ---- init / weight prep ----
  k_zero_f<<<392,256,0,stream>>>(stateF, 100352);
  k_zero_f<<<128,256,0,stream>>>(hc_enc, 32768);
  k_xT96b<<<19200,256,0,stream>>>(mel, xTb);
  k_padW96b2<<<384,256,0,stream>>>(l1fWih, w_l1f_h, w_l1f_l);
  k_padW96b2<<<384,256,0,stream>>>(l1bWih, w_l1b_h, w_l1b_l);
  k_whh_il8<<<1024,256,0,stream>>>(l1fWhh, whh1f);
  k_whh_il8<<<1024,256,0,stream>>>(l1bWhh, whh1b);
  k_whh_il8<<<1024,256,0,stream>>>(l2fWhh, whh2f);
  k_whh_il8<<<1024,256,0,stream>>>(l2bWhh, whh2b);
  k_cvt2<<<256,256,0,stream>>>(mW, w_m_h, w_m_l, 65536);
  k_psW<<<257,256,0,stream>>>(psW, psb, psW_p, psb_p);
  k_zero_b<<<2048,256,0,stream>>>(out1, 26214400);
  k_zero_b<<<2048,256,0,stream>>>(memB, 13107200);

  // ---- encoder layer 1: 10 chunks x 160 steps (gemmM, K=96) ----
  for (int c=0;c<10;++c){
    const int t0 = c*160;
    gemmM<false,bf16><<<dim3(8,40),256,0,stream>>>(xTb,96, 1600,160,t0, lens,1,0,
        (const short*)w_l1f_h,(const short*)w_l1f_l,96, l1fb, Pchf,1024, 96);
    gemmM<false,bf16><<<dim3(8,40),256,0,stream>>>(xTb,96, 1600,160,t0, lens,1,1,
        (const short*)w_l1b_h,(const short*)w_l1b_l,96, l1bb, Pchb,1024, 96);
    lstm8<<<dim3(32,2),1024,0,stream>>>(Pchf,Pchb, whh1f,whh1b, lens,1, t0,160, out1, 1600, hc_enc);
  }

  // ---- l2 weight hi/lo planes into R_X (xTb dead) ----
  k_cvt2<<<4096,256,0,stream>>>(l2fWih, w_l2f_h, w_l2f_l, 1048576);
  k_cvt2<<<4096,256,0,stream>>>(l2bWih, w_l2b_h, w_l2b_l, 1048576);

  // ---- encoder layer 2: 5 chunks x 160 steps (gemmM) ----
  k_zero_f<<<128,256,0,stream>>>(hc_enc, 32768);
  for (int c=0;c<5;++c){
    const int t0 = c*160;
    gemmM<false,bf16><<<dim3(8,40),256,0,stream>>>(out1,1024, 800,160,t0, lens,2,0,
        (const short*)w_l2f_h,(const short*)w_l2f_l,1024, l2fb, Pchf,1024, 1024);
    gemmM<false,bf16><<<dim3(8,40),256,0,stream>>>(out1,1024, 800,160,t0, lens,2,1,
        (const short*)w_l2b_h,(const short*)w_l2b_l,1024, l2bb, Pchb,1024, 1024);
    lstm8<<<dim3(32,2),1024,0,stream>>>(Pchf,Pchb, whh2f,whh2b, lens,2, t0,160, memB, 800, hc_enc);
  }

  // ---- decoder precompute ----
  gemmM<false,float><<<dim3(1,200),256,0,stream>>>(memB,512, 0,0,0, nullptr,0,0,
      (const short*)w_m_h,(const short*)w_m_l,512, (const float*)nullptr, PM,128, 512);
  k_zero_b<<<2048,256,0,stream>>>(dseqB, 2686976);
  k_dseqb<<<10304,256,0,stream>>>(start, dec_in, dseqB);
  k_wpd<<<4096,256,0,stream>>>(decWih, w_pd_h, w_pd_l);
  gemmM<false,bf16><<<dim3(16,41),256,0,stream>>>(dseqB,512, 0,0,0, nullptr,0,0,
      (const short*)w_pd_h,(const short*)w_pd_l,512, decb, Pd,2048, 512);
  k_zero_f<<<2048,256,0,stream>>>(hallctx, 5308416);

  // ---- decoder: 161 steps x 2 kernels ----
  for (int s=0; s<161; ++s){
    dec_g<<<dim3(32,8),256,0,stream>>>(Pd, decWih, decWhh, h_state, ctx_state, g_buf, s);
    dec_rest<<<32,1024,0,stream>>>(g_buf, qW, convW, locW, vW, PM, memB, lens,
                                   h_state, c_state, ctx_state, aw_state, awc_state,
                                   hallctx, outA, s);
  }

  // ---- deferred projections + scatter ----
  gemm64<true ,float,float><<<dim3(8,81),256,0,stream>>>(hallctx,1024, 0,0,0, nullptr,0,0,
                                                phW,1024, phb, hid,512, 1024);
  gemm64<false,float,float><<<dim3(2,81),256,0,stream>>>(hid,512, 0,0,0, nullptr,0,0,
                                                psW_p,512, psb_p, logitb,128, 512);
  k_scat_h<<<10304,256,0,stream>>>(hid, outH);
  k_scat_l<<<2033,256,0,stream>>>(logitb, outL);
}